// Round 11
// baseline (11378.122 us; speedup 1.0000x reference)
//
#include <hip/hip_runtime.h>

#define HH   100
#define LL   4096
#define NT   512
#define NLDSROW 176          // W_all rows 0..175 (= Whh0 gates 0..175) streamed from LDS
#define RB0  176             // first register-resident row
#define NMERGE 156           // task rows 0..155 merged into dot loop (qid==row, h1-class match)
// Row space r in [0,1200): [0,400) Whh0 (src h1), [400,800) Wih1 (src h1), [800,1200) Whh1 (src h2).
// Thread: qid=tid>>1 (4 rows RB0+4q..+3), half=tid&1 (cols 50h..50h+49). 200 weight floats as 100 named v2f.
// Task rows 0..155: merged into dot loop of thread qid (shares hv loads). Rows 156..175 (40 units):
// unmerged on wave 5 (tid 320..359). wq halves staggered +4 floats to break 8-way bank conflicts.

#define WQH  (NLDSROW*52 + 4)                // 9156 floats per half (staggered)
#define WQ_OFF   4096
#define H1_OFF   (WQ_OFF + 2*WQH)            // 4096 + 18312 = 22408
#define H2_OFF   (H1_OFF + 104)              // 22512
#define PART_OFF (H2_OFF + 104)              // 22616 (16B aligned)
#define Q_OFF    (PART_OFF + 2048)           // 24664
#define LDS_FLOATS (Q_OFF + 352)             // 25016 floats ~ 100 KB

typedef float v2f __attribute__((ext_vector_type(2)));
__device__ __forceinline__ v2f fma2(v2f a, v2f b, v2f c) { return __builtin_elementwise_fma(a, b, c); }
__device__ __forceinline__ v2f v2c(float2 f) { v2f r; r.x = f.x; r.y = f.y; return r; }

__device__ __forceinline__ float sigmoidf_(float x) {
    return 1.0f / (1.0f + __expf(-x));
}
__device__ __forceinline__ float tanhf_(float x) {
    return 1.0f - 2.0f / (__expf(2.0f * x) + 1.0f);
}

// ---- named register rows: 25 v2f = 50 floats (no alloca) ----
#define DECLROW(n) v2f n##_0,n##_1,n##_2,n##_3,n##_4,n##_5,n##_6,n##_7,n##_8,n##_9,n##_10,n##_11, \
                       n##_12,n##_13,n##_14,n##_15,n##_16,n##_17,n##_18,n##_19,n##_20,n##_21,n##_22,n##_23,n##_24;
#define LOADROW(n, P) { const float2* q2_ = reinterpret_cast<const float2*>(P); \
  n##_0=v2c(q2_[0]);   n##_1=v2c(q2_[1]);   n##_2=v2c(q2_[2]);   n##_3=v2c(q2_[3]);   n##_4=v2c(q2_[4]); \
  n##_5=v2c(q2_[5]);   n##_6=v2c(q2_[6]);   n##_7=v2c(q2_[7]);   n##_8=v2c(q2_[8]);   n##_9=v2c(q2_[9]); \
  n##_10=v2c(q2_[10]); n##_11=v2c(q2_[11]); n##_12=v2c(q2_[12]); n##_13=v2c(q2_[13]); n##_14=v2c(q2_[14]); \
  n##_15=v2c(q2_[15]); n##_16=v2c(q2_[16]); n##_17=v2c(q2_[17]); n##_18=v2c(q2_[18]); n##_19=v2c(q2_[19]); \
  n##_20=v2c(q2_[20]); n##_21=v2c(q2_[21]); n##_22=v2c(q2_[22]); n##_23=v2c(q2_[23]); n##_24=v2c(q2_[24]); }

// ---- dot step j: h float4 shared by 4 register rows AND (if mtask) the merged task row ----
#define STEP(j,p,q) { float4 hv = hb4[j]; v2f hl, hh; hl.x=hv.x; hl.y=hv.y; hh.x=hv.z; hh.y=hv.w; \
  a0=fma2(wa_##p,hl,a0); a0=fma2(wa_##q,hh,a0); \
  a1=fma2(wb_##p,hl,a1); a1=fma2(wb_##q,hh,a1); \
  a2=fma2(wc_##p,hl,a2); a2=fma2(wc_##q,hh,a2); \
  a3=fma2(wd_##p,hl,a3); a3=fma2(wd_##q,hh,a3); \
  if (mtask) { float4 wv = tp4[j]; v2f wl_,wh_; wl_.x=wv.x; wl_.y=wv.y; wh_.x=wv.z; wh_.y=wv.w; \
    tq=fma2(wl_,hl,tq); tq=fma2(wh_,hh,tq); } }

// ---- unmerged task step (wave 5: rows 156..175, h1-source) ----
#define UTS(j) { float4 wv = utp4[j]; float4 hv = uh4[j]; v2f wl_,wh_,hl_,hh_; \
  wl_.x=wv.x; wl_.y=wv.y; wh_.x=wv.z; wh_.y=wv.w; hl_.x=hv.x; hl_.y=hv.y; hh_.x=hv.z; hh_.y=hv.w; \
  uq=fma2(wl_,hl_,uq); uq=fma2(wh_,hh_,uq); }

__global__ __attribute__((amdgpu_flat_work_group_size(NT, NT)))
           __attribute__((amdgpu_waves_per_eu(2, 2)))
void lstm_r11_kernel(const float* __restrict__ x_seq,
                     const float* __restrict__ Wih0,
                     const float* __restrict__ Whh0,
                     const float* __restrict__ bih0,
                     const float* __restrict__ bhh0,
                     const float* __restrict__ Wih1,
                     const float* __restrict__ Whh1,
                     const float* __restrict__ bih1,
                     const float* __restrict__ bhh1,
                     const float* __restrict__ Wlin,
                     const float* __restrict__ blin,
                     float* __restrict__ out)
{
    extern __shared__ float lds[];
    float* x_s    = lds;                 // [4096]
    float* wq     = lds + WQ_OFF;        // [2][176][52] rows, halves staggered by +4 floats
    float* h1_s   = lds + H1_OFF;        // [104] padded: h[e] at e + 2*(e>=50); pads zeroed
    float* h2_s   = lds + H2_OFF;        // [104]
    float* part_s = lds + PART_OFF;      // [2048]: slot = ((row-176)>>2) + ((row-176)&3)*256 + half*1024
    float* q_s    = lds + Q_OFF;         // [352]: row + 176*half

    const int tid  = threadIdx.x;
    const int half = tid & 1;
    const int qid  = tid >> 1;           // 0..255
    const int rowbase = RB0 + 4*qid;     // 176..1196, region-aligned

    // ---- prologue: x ----
    {
        const float4* src = reinterpret_cast<const float4*>(x_seq);
        float4*       dst = reinterpret_cast<float4*>(x_s);
        for (int i = tid; i < LL/4; i += NT) dst[i] = src[i];
    }
    // ---- wq: contiguous rows [half(staggered)][row][52] of Whh0 rows 0..175 ----
    for (int idx = tid; idx < 2*NLDSROW*50; idx += NT) {
        int hf  = idx / (NLDSROW*50);
        int rem = idx - hf*(NLDSROW*50);
        int row = rem / 50;
        int c   = rem - row*50;
        wq[hf*WQH + row*52 + c] = Whh0[row*HH + hf*50 + c];
    }
    if (tid < 104) { h1_s[tid] = 0.0f; h2_s[tid] = 0.0f; }

    // ---- per-thread register weights: 4 rows x 50 cols as 100 named v2f ----
    const float* M; int r0;
    if (rowbase < 400)      { M = Whh0; r0 = rowbase; }
    else if (rowbase < 800) { M = Wih1; r0 = rowbase - 400; }
    else                    { M = Whh1; r0 = rowbase - 800; }

    DECLROW(wa) DECLROW(wb) DECLROW(wc) DECLROW(wd)
    LOADROW(wa, M + (r0+0)*HH + half*50)
    LOADROW(wb, M + (r0+1)*HH + half*50)
    LOADROW(wc, M + (r0+2)*HH + half*50)
    LOADROW(wd, M + (r0+3)*HH + half*50)

    // bias / wx per row (meaning depends on half; applied via xvs = half? xt : 1)
    float bw0, bw1, bw2, bw3;
    {
        const int ra = rowbase, rb = rowbase+1, rc = rowbase+2, rd = rowbase+3;
        if (half == 0) {
            bw0 = (ra < 400) ? (bih0[ra] + bhh0[ra]) : (ra < 800) ? (bih1[ra-400] + bhh1[ra-400]) : 0.0f;
            bw1 = (rb < 400) ? (bih0[rb] + bhh0[rb]) : (rb < 800) ? (bih1[rb-400] + bhh1[rb-400]) : 0.0f;
            bw2 = (rc < 400) ? (bih0[rc] + bhh0[rc]) : (rc < 800) ? (bih1[rc-400] + bhh1[rc-400]) : 0.0f;
            bw3 = (rd < 400) ? (bih0[rd] + bhh0[rd]) : (rd < 800) ? (bih1[rd-400] + bhh1[rd-400]) : 0.0f;
        } else {
            bw0 = (ra < 400) ? Wih0[ra] : 0.0f;
            bw1 = (rb < 400) ? Wih0[rb] : 0.0f;
            bw2 = (rc < 400) ? Wih0[rc] : 0.0f;
            bw3 = (rd < 400) ? Wih0[rd] : 0.0f;
        }
    }

    // ---- merged task (rows 0..155 on qid==row; shares dot's h1 loads) ----
    const bool mtask = (qid < NMERGE);
    const float4* tp4 = reinterpret_cast<const float4*>(wq + half*WQH + (mtask ? qid : 0)*52);
    float lb = 0.0f;
    if (mtask) lb = half ? Wih0[qid] : (bih0[qid] + bhh0[qid]);

    // ---- unmerged task (rows 156..175, 40 units on wave 5: tid 320..359) ----
    const bool utask = (tid >= 320) && (tid < 360);
    const int  urow  = NMERGE + ((tid - 320) >> 1);          // 156..175 (task half == own half)
    const float4* utp4 = reinterpret_cast<const float4*>(wq + half*WQH + (utask ? urow : 0)*52);
    const float4* uh4  = reinterpret_cast<const float4*>(h1_s + half*52);
    float ulb = 0.0f;
    if (utask) ulb = half ? Wih0[urow] : (bih0[urow] + bhh0[urow]);

    // h source for register dots (wave-cheap LDS broadcast)
    const float4* hb4 = reinterpret_cast<const float4*>(
        ((rowbase < 800) ? h1_s : h2_s) + half*52);

    const float wl = (tid < HH) ? Wlin[tid] : 0.0f;
    const int slotbase = qid + half*1024;
    float c0 = 0.0f, c1 = 0.0f;

    __syncthreads();

    for (int t = 0; t <= LL; ++t) {
        const float xt  = x_s[(t < LL) ? t : (LL-1)];
        const float xvs = half ? xt : 1.0f;

        // === dot phase: 4 register rows + merged task row, packed-FMA ===
        {
            v2f a0 = {0.f,0.f}, a1 = {0.f,0.f}, a2 = {0.f,0.f}, a3 = {0.f,0.f};
            v2f tq = {0.f,0.f};
            STEP(0,0,1)   STEP(1,2,3)   STEP(2,4,5)   STEP(3,6,7)
            STEP(4,8,9)   STEP(5,10,11) STEP(6,12,13) STEP(7,14,15)
            STEP(8,16,17) STEP(9,18,19) STEP(10,20,21) STEP(11,22,23)
            {   // tail pair (cols 48,49); hb4[12].xy are h48,h49 (pads are zeroed)
                float4 hv = hb4[12]; v2f hl; hl.x = hv.x; hl.y = hv.y;
                a0 = fma2(wa_24, hl, a0);
                a1 = fma2(wb_24, hl, a1);
                a2 = fma2(wc_24, hl, a2);
                a3 = fma2(wd_24, hl, a3);
                if (mtask) {
                    float2 wv2 = reinterpret_cast<const float2*>(tp4)[24];
                    v2f w_; w_.x = wv2.x; w_.y = wv2.y;
                    tq = fma2(w_, hl, tq);
                }
            }
            part_s[slotbase + 0*256] = fmaf(bw0, xvs, a0.x + a0.y);
            part_s[slotbase + 1*256] = fmaf(bw1, xvs, a1.x + a1.y);
            part_s[slotbase + 2*256] = fmaf(bw2, xvs, a2.x + a2.y);
            part_s[slotbase + 3*256] = fmaf(bw3, xvs, a3.x + a3.y);
            if (mtask) q_s[qid + half*NLDSROW] = fmaf(lb, xvs, tq.x + tq.y);
        }
        // === unmerged task rows 156..175 (wave 5 only; h1-source) ===
        if (utask) {
            v2f uq = {0.f,0.f};
            UTS(0) UTS(1) UTS(2) UTS(3) UTS(4)  UTS(5)
            UTS(6) UTS(7) UTS(8) UTS(9) UTS(10) UTS(11)
            {   // tail pair
                float2 wv2 = reinterpret_cast<const float2*>(utp4)[24];
                float2 hv2 = reinterpret_cast<const float2*>(uh4)[24];
                v2f w_, h_; w_.x = wv2.x; w_.y = wv2.y; h_.x = hv2.x; h_.y = hv2.y;
                uq = fma2(w_, h_, uq);
            }
            q_s[urow + half*NLDSROW] = fmaf(ulb, xvs, uq.x + uq.y);
        }
        __syncthreads();

        // === gating phase ===
        if (tid < HH) {                          // L0 gating -> h1(t)
            const int j = tid;
            float g[4];
            #pragma unroll
            for (int k = 0; k < 4; ++k) {
                int r = j + k*100;
                if (r < NLDSROW) {
                    g[k] = q_s[r] + q_s[r + NLDSROW];
                } else {
                    int rr = r - RB0;
                    int b  = (rr >> 2) + ((rr & 3) << 8);
                    g[k] = part_s[b] + part_s[b + 1024];
                }
            }
            if (t < LL) {
                c0 = sigmoidf_(g[1])*c0 + sigmoidf_(g[0])*tanhf_(g[2]);
                h1_s[j + 2*(j >= 50)] = sigmoidf_(g[3])*tanhf_(c0);
            }
        } else if (tid >= 128 && tid < 128 + HH) {   // L1 gating -> h2(t-1)
            if (t >= 1) {
                const int j = tid - 128;
                float v[4];
                #pragma unroll
                for (int k = 0; k < 4; ++k) {
                    int g = j + k*100;
                    int rr1 = (400 + g) - RB0;
                    int b1i = (rr1 >> 2) + ((rr1 & 3) << 8);
                    int rr2 = (800 + g) - RB0;
                    int b2i = (rr2 >> 2) + ((rr2 & 3) << 8);
                    v[k] = (part_s[b1i] + part_s[b1i + 1024])
                         + (part_s[b2i] + part_s[b2i + 1024]);
                }
                c1 = sigmoidf_(v[1])*c1 + sigmoidf_(v[0])*tanhf_(v[2]);
                h2_s[j + 2*(j >= 50)] = sigmoidf_(v[3])*tanhf_(c1);
            }
        }
        __syncthreads();
    }

    // ---- final projection: out = h2(L-1) . Wlin + blin ----
    if (tid < HH) part_s[tid] = wl * h2_s[tid + 2*(tid >= 50)];
    __syncthreads();
    if (tid == 0) {
        float s = 0.0f;
        for (int k = 0; k < HH; ++k) s += part_s[k];
        out[0] = s + blin[0];
    }
}

extern "C" void kernel_launch(void* const* d_in, const int* in_sizes, int n_in,
                              void* d_out, int out_size, void* d_ws, size_t ws_size,
                              hipStream_t stream) {
    (void)in_sizes; (void)n_in; (void)out_size; (void)d_ws; (void)ws_size;

    const float* x_seq = (const float*)d_in[0];
    const float* Wih0  = (const float*)d_in[1];
    const float* Whh0  = (const float*)d_in[2];
    const float* bih0  = (const float*)d_in[3];
    const float* bhh0  = (const float*)d_in[4];
    const float* Wih1  = (const float*)d_in[5];
    const float* Whh1  = (const float*)d_in[6];
    const float* bih1  = (const float*)d_in[7];
    const float* bhh1  = (const float*)d_in[8];
    const float* Wlin  = (const float*)d_in[9];
    const float* blin  = (const float*)d_in[10];
    float* out = (float*)d_out;

    static bool attr_set = false;
    if (!attr_set) {
        hipFuncSetAttribute((const void*)lstm_r11_kernel,
                            hipFuncAttributeMaxDynamicSharedMemorySize,
                            LDS_FLOATS * (int)sizeof(float));
        attr_set = true;
    }

    hipLaunchKernelGGL(lstm_r11_kernel, dim3(1), dim3(NT),
                       LDS_FLOATS * sizeof(float), stream,
                       x_seq, Wih0, Whh0, bih0, bhh0,
                       Wih1, Whh1, bih1, bhh1, Wlin, blin, out);
}

// Round 12
// 4280.952 us; speedup vs baseline: 2.6578x; 2.6578x over previous
//
#include <hip/hip_runtime.h>

#define HH 100
#define LL 4096
#define NT 512

// ---- workspace layout: h1 stream [LL][128] floats, then flags [LL] ints ----
#define WS_H1_FLOATS (LL*128)
#define WS_NEEDED ((size_t)WS_H1_FLOATS*4 + (size_t)LL*4)

typedef float v2f __attribute__((ext_vector_type(2)));
__device__ __forceinline__ v2f fma2(v2f a, v2f b, v2f c) { return __builtin_elementwise_fma(a, b, c); }
__device__ __forceinline__ v2f v2c(float2 f) { v2f r; r.x = f.x; r.y = f.y; return r; }

__device__ __forceinline__ float sigmoidf_(float x) { return 1.0f / (1.0f + __expf(-x)); }
__device__ __forceinline__ float tanhf_(float x)    { return 1.0f - 2.0f / (__expf(2.0f * x) + 1.0f); }

// ---- named register rows: 25 v2f = 50 floats (no alloca) ----
#define DECLROW(n) v2f n##_0,n##_1,n##_2,n##_3,n##_4,n##_5,n##_6,n##_7,n##_8,n##_9,n##_10,n##_11, \
                       n##_12,n##_13,n##_14,n##_15,n##_16,n##_17,n##_18,n##_19,n##_20,n##_21,n##_22,n##_23,n##_24;
#define LOADROW(n, P) { const float2* q2_ = reinterpret_cast<const float2*>(P); \
  n##_0=v2c(q2_[0]);   n##_1=v2c(q2_[1]);   n##_2=v2c(q2_[2]);   n##_3=v2c(q2_[3]);   n##_4=v2c(q2_[4]); \
  n##_5=v2c(q2_[5]);   n##_6=v2c(q2_[6]);   n##_7=v2c(q2_[7]);   n##_8=v2c(q2_[8]);   n##_9=v2c(q2_[9]); \
  n##_10=v2c(q2_[10]); n##_11=v2c(q2_[11]); n##_12=v2c(q2_[12]); n##_13=v2c(q2_[13]); n##_14=v2c(q2_[14]); \
  n##_15=v2c(q2_[15]); n##_16=v2c(q2_[16]); n##_17=v2c(q2_[17]); n##_18=v2c(q2_[18]); n##_19=v2c(q2_[19]); \
  n##_20=v2c(q2_[20]); n##_21=v2c(q2_[21]); n##_22=v2c(q2_[22]); n##_23=v2c(q2_[23]); n##_24=v2c(q2_[24]); }

// ---- 2-row dot step (WG0) ----
#define STEP2(j,p,q) { float4 hv = hb4[j]; v2f hl, hh; hl.x=hv.x; hl.y=hv.y; hh.x=hv.z; hh.y=hv.w; \
  a0=fma2(wa_##p,hl,a0); a0=fma2(wa_##q,hh,a0); \
  a1=fma2(wb_##p,hl,a1); a1=fma2(wb_##q,hh,a1); }

// ---- 4-row dot step (WG1) ----
#define STEP4(j,p,q) { float4 hv = hb4[j]; v2f hl, hh; hl.x=hv.x; hl.y=hv.y; hh.x=hv.z; hh.y=hv.w; \
  a0=fma2(wa_##p,hl,a0); a0=fma2(wa_##q,hh,a0); \
  a1=fma2(wb_##p,hl,a1); a1=fma2(wb_##q,hh,a1); \
  a2=fma2(wc_##p,hl,a2); a2=fma2(wc_##q,hh,a2); \
  a3=fma2(wd_##p,hl,a3); a3=fma2(wd_##q,hh,a3); }

// =====================================================================
// Pipelined 2-WG kernel: block 0 = layer 0 (producer), block 1 = layer 1
// =====================================================================
#define P_LDS_FLOATS 5120

__global__ __attribute__((amdgpu_flat_work_group_size(NT, NT)))
           __attribute__((amdgpu_waves_per_eu(2, 2)))
void lstm_pipe2(const float* __restrict__ x_seq,  const float* __restrict__ Wih0,
                const float* __restrict__ Whh0,   const float* __restrict__ bih0,
                const float* __restrict__ bhh0,   const float* __restrict__ Wih1,
                const float* __restrict__ Whh1,   const float* __restrict__ bih1,
                const float* __restrict__ bhh1,   const float* __restrict__ Wlin,
                const float* __restrict__ blin,   float* __restrict__ ws_h1,
                int* __restrict__ ws_flag,        float* __restrict__ out)
{
    extern __shared__ float lds[];
    const int tid = threadIdx.x;

    if (blockIdx.x == 0) {
        // ---------------- WG0: layer 0 -> h1 stream ----------------
        float* x_s   = lds;            // [4096]
        float* h1_s  = lds + 4096;     // [104] padded (e at e+2*(e>=50)), pads zero
        float* part0 = lds + 4200;     // [2 halves][400 rows]

        const int half = tid & 1;
        const int q    = tid >> 1;           // 0..255
        const bool act = (q < 200);
        const int r0   = act ? 2*q : 0;      // rows r0, r0+1

        {   const float4* src = reinterpret_cast<const float4*>(x_seq);
            float4* dst = reinterpret_cast<float4*>(x_s);
            for (int i = tid; i < LL/4; i += NT) dst[i] = src[i]; }
        if (tid < 104) h1_s[tid] = 0.0f;

        DECLROW(wa) DECLROW(wb)
        LOADROW(wa, Whh0 + (r0+0)*HH + half*50)
        LOADROW(wb, Whh0 + (r0+1)*HH + half*50)
        float bw0 = 0.f, bw1 = 0.f;
        if (act) {
            if (half == 0) { bw0 = bih0[r0] + bhh0[r0]; bw1 = bih0[r0+1] + bhh0[r0+1]; }
            else           { bw0 = Wih0[r0];            bw1 = Wih0[r0+1]; }
        }
        const float4* hb4 = reinterpret_cast<const float4*>(h1_s + half*52);
        float c0 = 0.0f;
        __syncthreads();

        for (int t = 0; t < LL; ++t) {
            const float xt  = x_s[t];
            const float xvs = half ? xt : 1.0f;
            if (act) {
                v2f a0 = {0.f,0.f}, a1 = {0.f,0.f};
                STEP2(0,0,1)   STEP2(1,2,3)   STEP2(2,4,5)   STEP2(3,6,7)
                STEP2(4,8,9)   STEP2(5,10,11) STEP2(6,12,13) STEP2(7,14,15)
                STEP2(8,16,17) STEP2(9,18,19) STEP2(10,20,21) STEP2(11,22,23)
                { float4 hv = hb4[12]; v2f hl; hl.x = hv.x; hl.y = hv.y;
                  a0 = fma2(wa_24, hl, a0); a1 = fma2(wb_24, hl, a1); }
                float* pw = part0 + half*400 + r0;
                pw[0] = fmaf(bw0, xvs, a0.x + a0.y);
                pw[1] = fmaf(bw1, xvs, a1.x + a1.y);
            }
            __syncthreads();
            if (tid < 100) {
                const int j = tid;
                float G0 = part0[j]       + part0[400 + j];
                float G1 = part0[j + 100] + part0[500 + j];
                float G2 = part0[j + 200] + part0[600 + j];
                float G3 = part0[j + 300] + part0[700 + j];
                c0 = sigmoidf_(G1)*c0 + sigmoidf_(G0)*tanhf_(G2);
                float h = sigmoidf_(G3)*tanhf_(c0);
                h1_s[j + 2*(j >= 50)] = h;
                __hip_atomic_store(&ws_h1[t*128 + j], h, __ATOMIC_RELAXED, __HIP_MEMORY_SCOPE_AGENT);
            }
            __syncthreads();
            if (tid == 0)
                __hip_atomic_store(&ws_flag[t], 1, __ATOMIC_RELEASE, __HIP_MEMORY_SCOPE_AGENT);
        }
    } else {
        // ---------------- WG1: layer 1 + output ----------------
        float* h1c   = lds;            // [104] current h1(t), padded
        float* h2_s  = lds + 104;      // [104] h2(t-1), padded
        float* part1 = lds + 208;      // [2 halves][2 classes][400 rows] = 1600
        float* red   = lds + 1808;     // [100]

        // dot threads: tids 0..399: c=tid/200, h=(tid%200)/100, b=tid%100 -> rows 4b..4b+3
        const bool dotter = (tid < 400);
        const int  c    = dotter ? (tid / 200) : 0;
        const int  rem  = dotter ? (tid % 200) : 0;
        const int  half = rem / 100;
        const int  b    = rem % 100;
        const int  rb   = 4*b;
        const float* mat = c ? Whh1 : Wih1;

        DECLROW(wa) DECLROW(wb) DECLROW(wc) DECLROW(wd)
        LOADROW(wa, mat + (rb+0)*HH + half*50)
        LOADROW(wb, mat + (rb+1)*HH + half*50)
        LOADROW(wc, mat + (rb+2)*HH + half*50)
        LOADROW(wd, mat + (rb+3)*HH + half*50)
        float bw0=0.f, bw1=0.f, bw2=0.f, bw3=0.f;
        if (dotter && c == 0 && half == 0) {
            bw0 = bih1[rb]   + bhh1[rb];
            bw1 = bih1[rb+1] + bhh1[rb+1];
            bw2 = bih1[rb+2] + bhh1[rb+2];
            bw3 = bih1[rb+3] + bhh1[rb+3];
        }
        const float4* hb4 = reinterpret_cast<const float4*>((c ? h2_s : h1c) + half*52);
        const int pbase = half*800 + c*400 + rb;

        // gate+load threads: tids 400..499, j = tid-400
        const bool gl = (tid >= 400) && (tid < 500);
        const int  j  = tid - 400;
        const float wl = gl ? Wlin[j] : 0.0f;
        float c1 = 0.0f;

        if (tid < 104) { h1c[tid] = 0.0f; h2_s[tid] = 0.0f; }
        __syncthreads();
        if (gl) {
            while (__hip_atomic_load(&ws_flag[0], __ATOMIC_ACQUIRE, __HIP_MEMORY_SCOPE_AGENT) == 0) {}
            float h0 = __hip_atomic_load(&ws_h1[j], __ATOMIC_RELAXED, __HIP_MEMORY_SCOPE_AGENT);
            h1c[j + 2*(j >= 50)] = h0;
            while (__hip_atomic_load(&ws_flag[1], __ATOMIC_ACQUIRE, __HIP_MEMORY_SCOPE_AGENT) == 0) {}
        }
        __syncthreads();

        for (int t = 0; t < LL; ++t) {
            float hnf = 0.0f; int f2v = 1;
            if (gl) {   // prefetch h1(t+1) (flag[t+1] confirmed last iter) + poll flag[t+2]
                const int tp1 = (t+1 < LL) ? t+1 : LL-1;
                const int tp2 = (t+2 < LL) ? t+2 : LL-1;
                hnf = __hip_atomic_load(&ws_h1[tp1*128 + j], __ATOMIC_RELAXED, __HIP_MEMORY_SCOPE_AGENT);
                f2v = __hip_atomic_load(&ws_flag[tp2], __ATOMIC_ACQUIRE, __HIP_MEMORY_SCOPE_AGENT);
            }
            if (dotter) {
                v2f a0 = {0.f,0.f}, a1 = {0.f,0.f}, a2 = {0.f,0.f}, a3 = {0.f,0.f};
                STEP4(0,0,1)   STEP4(1,2,3)   STEP4(2,4,5)   STEP4(3,6,7)
                STEP4(4,8,9)   STEP4(5,10,11) STEP4(6,12,13) STEP4(7,14,15)
                STEP4(8,16,17) STEP4(9,18,19) STEP4(10,20,21) STEP4(11,22,23)
                { float4 hv = hb4[12]; v2f hl; hl.x = hv.x; hl.y = hv.y;
                  a0 = fma2(wa_24, hl, a0); a1 = fma2(wb_24, hl, a1);
                  a2 = fma2(wc_24, hl, a2); a3 = fma2(wd_24, hl, a3); }
                reinterpret_cast<float4*>(part1 + pbase)[0] =
                    make_float4(a0.x + a0.y + bw0, a1.x + a1.y + bw1,
                                a2.x + a2.y + bw2, a3.x + a3.y + bw3);
            }
            __syncthreads();
            if (gl) {
                // gate h2(t): G = (Wih1 h0+h1) + (Whh1 h0+h1)
                float G0 = (part1[j]       + part1[800+j])       + (part1[400+j]       + part1[1200+j]);
                float G1 = (part1[j+100]   + part1[900+j])       + (part1[500+j]       + part1[1300+j]);
                float G2 = (part1[j+200]   + part1[1000+j])      + (part1[600+j]       + part1[1400+j]);
                float G3 = (part1[j+300]   + part1[1100+j])      + (part1[700+j]       + part1[1500+j]);
                c1 = sigmoidf_(G1)*c1 + sigmoidf_(G0)*tanhf_(G2);
                h2_s[j + 2*(j >= 50)] = sigmoidf_(G3)*tanhf_(c1);
                // install h1(t+1) for next step's dots
                h1c[j + 2*(j >= 50)] = hnf;
                while (f2v == 0) {
                    const int tp2 = (t+2 < LL) ? t+2 : LL-1;
                    f2v = __hip_atomic_load(&ws_flag[tp2], __ATOMIC_ACQUIRE, __HIP_MEMORY_SCOPE_AGENT);
                }
            }
            __syncthreads();
        }
        if (gl) red[j] = wl * h2_s[j + 2*(j >= 50)];
        __syncthreads();
        if (tid == 0) {
            float s = blin[0];
            for (int k = 0; k < HH; ++k) s += red[k];
            out[0] = s;
        }
    }
}

// =====================================================================
// Fallback: proven single-WG kernel (R10, 6.5 ms) when ws is too small
// =====================================================================
#define NLDSROW 176
#define RB0  176
#define WQ_OFF   4096
#define H1_OFF   (WQ_OFF + 2*NLDSROW*52)
#define H2_OFF   (H1_OFF + 104)
#define PART_OFF (H2_OFF + 104)
#define Q_OFF    (PART_OFF + 2048)
#define LDS_FLOATS (Q_OFF + 352)

#define TSK(j) { float4 wv = tp4[j]; float4 hv = hb4t[j]; v2f wl_,wh_,hl_,hh_; \
  wl_.x=wv.x; wl_.y=wv.y; wh_.x=wv.z; wh_.y=wv.w; hl_.x=hv.x; hl_.y=hv.y; hh_.x=hv.z; hh_.y=hv.w; \
  tq=fma2(wl_,hl_,tq); tq=fma2(wh_,hh_,tq); }

__global__ __attribute__((amdgpu_flat_work_group_size(NT, NT)))
           __attribute__((amdgpu_waves_per_eu(2, 2)))
void lstm_v256_kernel(const float* __restrict__ x_seq, const float* __restrict__ Wih0,
                      const float* __restrict__ Whh0,  const float* __restrict__ bih0,
                      const float* __restrict__ bhh0,  const float* __restrict__ Wih1,
                      const float* __restrict__ Whh1,  const float* __restrict__ bih1,
                      const float* __restrict__ bhh1,  const float* __restrict__ Wlin,
                      const float* __restrict__ blin,  float* __restrict__ out)
{
    extern __shared__ float lds[];
    float* x_s    = lds;
    float* wq     = lds + WQ_OFF;
    float* h1_s   = lds + H1_OFF;
    float* h2_s   = lds + H2_OFF;
    float* part_s = lds + PART_OFF;
    float* q_s    = lds + Q_OFF;

    const int tid  = threadIdx.x;
    const int half = tid & 1;
    const int qid  = tid >> 1;
    const int rowbase = RB0 + 4*qid;

    {   const float4* src = reinterpret_cast<const float4*>(x_seq);
        float4* dst = reinterpret_cast<float4*>(x_s);
        for (int i = tid; i < LL/4; i += NT) dst[i] = src[i]; }
    for (int idx = tid; idx < 2*NLDSROW*50; idx += NT) {
        int hf  = idx / (NLDSROW*50);
        int rem = idx - hf*(NLDSROW*50);
        int row = rem / 50;
        int cc  = rem - row*50;
        wq[(hf*NLDSROW + row)*52 + cc] = Whh0[row*HH + hf*50 + cc];
    }
    if (tid < 104) { h1_s[tid] = 0.0f; h2_s[tid] = 0.0f; }

    const float* M; int r0;
    if (rowbase < 400)      { M = Whh0; r0 = rowbase; }
    else if (rowbase < 800) { M = Wih1; r0 = rowbase - 400; }
    else                    { M = Whh1; r0 = rowbase - 800; }

    DECLROW(wa) DECLROW(wb) DECLROW(wc) DECLROW(wd)
    LOADROW(wa, M + (r0+0)*HH + half*50)
    LOADROW(wb, M + (r0+1)*HH + half*50)
    LOADROW(wc, M + (r0+2)*HH + half*50)
    LOADROW(wd, M + (r0+3)*HH + half*50)

    float bw0, bw1, bw2, bw3;
    {
        const int ra = rowbase, rb = rowbase+1, rc = rowbase+2, rd = rowbase+3;
        if (half == 0) {
            bw0 = (ra < 400) ? (bih0[ra] + bhh0[ra]) : (ra < 800) ? (bih1[ra-400] + bhh1[ra-400]) : 0.0f;
            bw1 = (rb < 400) ? (bih0[rb] + bhh0[rb]) : (rb < 800) ? (bih1[rb-400] + bhh1[rb-400]) : 0.0f;
            bw2 = (rc < 400) ? (bih0[rc] + bhh0[rc]) : (rc < 800) ? (bih1[rc-400] + bhh1[rc-400]) : 0.0f;
            bw3 = (rd < 400) ? (bih0[rd] + bhh0[rd]) : (rd < 800) ? (bih1[rd-400] + bhh1[rd-400]) : 0.0f;
        } else {
            bw0 = (ra < 400) ? Wih0[ra] : 0.0f;
            bw1 = (rb < 400) ? Wih0[rb] : 0.0f;
            bw2 = (rc < 400) ? Wih0[rc] : 0.0f;
            bw3 = (rd < 400) ? Wih0[rd] : 0.0f;
        }
    }

    float lb = 0.0f;
    if (tid < 2*NLDSROW) lb = half ? Wih0[qid] : (bih0[qid] + bhh0[qid]);
    const float4* tp4  = reinterpret_cast<const float4*>(wq + (half*NLDSROW + qid)*52);
    const float4* hb4t = reinterpret_cast<const float4*>(h1_s + half*52);
    const float4* hb4  = reinterpret_cast<const float4*>(((rowbase < 800) ? h1_s : h2_s) + half*52);

    const float wl = (tid < HH) ? Wlin[tid] : 0.0f;
    const int slotbase = qid + half*1024;
    float c0 = 0.0f, c1 = 0.0f;
    __syncthreads();

    for (int t = 0; t <= LL; ++t) {
        const float xt  = x_s[(t < LL) ? t : (LL-1)];
        const float xvs = half ? xt : 1.0f;
        {
            v2f a0 = {0.f,0.f}, a1 = {0.f,0.f}, a2 = {0.f,0.f}, a3 = {0.f,0.f};
            STEP4(0,0,1)   STEP4(1,2,3)   STEP4(2,4,5)   STEP4(3,6,7)
            STEP4(4,8,9)   STEP4(5,10,11) STEP4(6,12,13) STEP4(7,14,15)
            STEP4(8,16,17) STEP4(9,18,19) STEP4(10,20,21) STEP4(11,22,23)
            { float4 hv = hb4[12]; v2f hl; hl.x = hv.x; hl.y = hv.y;
              a0 = fma2(wa_24, hl, a0); a1 = fma2(wb_24, hl, a1);
              a2 = fma2(wc_24, hl, a2); a3 = fma2(wd_24, hl, a3); }
            part_s[slotbase + 0*256] = fmaf(bw0, xvs, a0.x + a0.y);
            part_s[slotbase + 1*256] = fmaf(bw1, xvs, a1.x + a1.y);
            part_s[slotbase + 2*256] = fmaf(bw2, xvs, a2.x + a2.y);
            part_s[slotbase + 3*256] = fmaf(bw3, xvs, a3.x + a3.y);
        }
        if (tid < 2*NLDSROW) {
            v2f tq = {0.f,0.f};
            TSK(0) TSK(1) TSK(2) TSK(3) TSK(4) TSK(5)
            TSK(6) TSK(7) TSK(8) TSK(9) TSK(10) TSK(11)
            { float4 wv = tp4[12]; float4 hv = hb4t[12];
              v2f wl_, hl_; wl_.x = wv.x; wl_.y = wv.y; hl_.x = hv.x; hl_.y = hv.y;
              tq = fma2(wl_, hl_, tq); }
            q_s[qid + half*NLDSROW] = fmaf(lb, xvs, tq.x + tq.y);
        }
        __syncthreads();
        if (tid < HH) {
            const int jj = tid;
            float g[4];
            #pragma unroll
            for (int k = 0; k < 4; ++k) {
                int r = jj + k*100;
                if (r < NLDSROW) g[k] = q_s[r] + q_s[r + NLDSROW];
                else { int rr = r - RB0; int bb = (rr >> 2) + ((rr & 3) << 8);
                       g[k] = part_s[bb] + part_s[bb + 1024]; }
            }
            if (t < LL) {
                c0 = sigmoidf_(g[1])*c0 + sigmoidf_(g[0])*tanhf_(g[2]);
                h1_s[jj + 2*(jj >= 50)] = sigmoidf_(g[3])*tanhf_(c0);
            }
        } else if (tid >= 128 && tid < 128 + HH) {
            if (t >= 1) {
                const int jj = tid - 128;
                float v[4];
                #pragma unroll
                for (int k = 0; k < 4; ++k) {
                    int g1i = jj + k*100;
                    int rr1 = (400 + g1i) - RB0; int b1i = (rr1 >> 2) + ((rr1 & 3) << 8);
                    int rr2 = (800 + g1i) - RB0; int b2i = (rr2 >> 2) + ((rr2 & 3) << 8);
                    v[k] = (part_s[b1i] + part_s[b1i + 1024]) + (part_s[b2i] + part_s[b2i + 1024]);
                }
                c1 = sigmoidf_(v[1])*c1 + sigmoidf_(v[0])*tanhf_(v[2]);
                h2_s[jj + 2*(jj >= 50)] = sigmoidf_(v[3])*tanhf_(c1);
            }
        }
        __syncthreads();
    }
    if (tid < HH) part_s[tid] = wl * h2_s[tid + 2*(tid >= 50)];
    __syncthreads();
    if (tid == 0) {
        float s = 0.0f;
        for (int k = 0; k < HH; ++k) s += part_s[k];
        out[0] = s + blin[0];
    }
}

extern "C" void kernel_launch(void* const* d_in, const int* in_sizes, int n_in,
                              void* d_out, int out_size, void* d_ws, size_t ws_size,
                              hipStream_t stream) {
    (void)in_sizes; (void)n_in; (void)out_size;

    const float* x_seq = (const float*)d_in[0];
    const float* Wih0  = (const float*)d_in[1];
    const float* Whh0  = (const float*)d_in[2];
    const float* bih0  = (const float*)d_in[3];
    const float* bhh0  = (const float*)d_in[4];
    const float* Wih1  = (const float*)d_in[5];
    const float* Whh1  = (const float*)d_in[6];
    const float* bih1  = (const float*)d_in[7];
    const float* bhh1  = (const float*)d_in[8];
    const float* Wlin  = (const float*)d_in[9];
    const float* blin  = (const float*)d_in[10];
    float* out = (float*)d_out;

    if (d_ws != nullptr && ws_size >= WS_NEEDED) {
        float* ws_h1  = (float*)d_ws;
        int*   ws_flg = (int*)((char*)d_ws + (size_t)WS_H1_FLOATS*4);
        hipMemsetAsync(ws_flg, 0, LL*sizeof(int), stream);
        hipLaunchKernelGGL(lstm_pipe2, dim3(2), dim3(NT),
                           P_LDS_FLOATS*sizeof(float), stream,
                           x_seq, Wih0, Whh0, bih0, bhh0,
                           Wih1, Whh1, bih1, bhh1, Wlin, blin,
                           ws_h1, ws_flg, out);
    } else {
        static bool attr_set = false;
        if (!attr_set) {
            hipFuncSetAttribute((const void*)lstm_v256_kernel,
                                hipFuncAttributeMaxDynamicSharedMemorySize,
                                LDS_FLOATS * (int)sizeof(float));
            attr_set = true;
        }
        hipLaunchKernelGGL(lstm_v256_kernel, dim3(1), dim3(NT),
                           LDS_FLOATS * sizeof(float), stream,
                           x_seq, Wih0, Whh0, bih0, bhh0,
                           Wih1, Whh1, bih1, bhh1, Wlin, blin, out);
    }
}